// Round 13
// baseline (64.250 us; speedup 1.0000x reference)
//
#include <hip/hip_runtime.h>

// AttentionConvFull: grouped 1x1 QKV + 5x5 per-channel local attention, FUSED.
// B=4, H=W=56, C=OC=256, G=8, Cg=32, K=5, pad=2.
//
// One block per (batch, 8x8 tile, group); 256 threads (c=tid&31, p0=tid>>5).
//   Stage:   x halo (12x12 px, 32 ch) -> xs LDS, coalesced float4, OOB zeroed.
//            Weight loads (24 x b128) issued BEFORE staging to overlap.
//   Merged QKV pass, 2 PIXELS PER ITER (9 iters): 6 independent FMA chains
//            cover v_fma latency; 16 b128 xs reads pipelined per iter.
//            k,v packed to bf16x2 in one u32, OVERWRITING xs in place (both
//            rows owned by the same half-wave group; reads precede writes;
//            per-wave in-order DS => race-free). q (pre-scaled log2e) -> qs.
//   Phase C: row-streaming attention; k,v unpacked from one b32; native
//            exp2 + rcp; single-pass softmax (logits bounded, f32-safe).
// LDS: xs 18KB + qs 8KB = 26.6KB. 2 barriers.
//
// R12 lesson: VGPR_Count=72 proved the compiler DEMOTED the 96-float weight
// set (reloads in-loop). float4-typed weight arrays + early issue fight this;
// VGPR report is the diagnostic (resident => ~100-128).
// R11/R12 model: VALU issue floor ~11us, wall 59us => latency-exposure bound;
// ILP (6 chains) + residency are the levers. LDS conflicts 0, HBM 4%.
//
// Register law (R1-R10): cap = 256/N for __launch_bounds__(256,N); no bounds
// => 64 (spills); no min-arg => allocator floats >128 (worse band). Spill
// signature: VGPR==cap AND WRITE_SIZE >> 12.5MB logical.

constexpr int TB = 4, TH = 56, TW = 56, TC = 256;
constexpr int G  = 8, CG = 32, PAD = 2;
constexpr int TILE = 8;
constexpr int HT = TILE + 2 * PAD;   // 12
constexpr int NT = TH / TILE;        // 7
constexpr int NPIX_HALO = HT * HT;   // 144
constexpr float LOG2E = 1.44269504088896340736f;

__global__ __launch_bounds__(256, 2)
void fused_attn_conv_kernel(const float* __restrict__ x,
                            const float* __restrict__ wq,
                            const float* __restrict__ wk,
                            const float* __restrict__ wv,
                            const float* __restrict__ rel,
                            const float* __restrict__ qemb,
                            float* __restrict__ out) {
    __shared__ float xs[NPIX_HALO][CG];    // 18 KB: x halo, then packed bf16(k,v)
    __shared__ float qs[TILE * TILE][CG];  // 8 KB: q*log2e for interior pixels

    const int bid  = blockIdx.x;
    const int g    = bid & 7;
    const int tile = bid >> 3;
    const int tj   = tile % NT;
    const int ti   = (tile / NT) % NT;
    const int b    = tile / (NT * NT);

    const int t  = threadIdx.x;
    const int c  = t & 31;
    const int p0 = t >> 5;

    const int oc = g * CG + c;           // global out-channel
    const int h0 = ti * TILE - PAD, w0 = tj * TILE - PAD;

    // ---- Issue weight loads FIRST (latency overlaps staging + barrier).
    float4 wq4[8], wk4[8], wv4[8];       // float4-typed: resist demotion
    {
        const float4* wqp = (const float4*)(wq + (size_t)oc * CG);
        const float4* wkp = (const float4*)(wk + (size_t)oc * CG);
        const float4* wvp = (const float4*)(wv + (size_t)oc * CG);
#pragma unroll
        for (int i = 0; i < 8; ++i) { wq4[i] = wqp[i]; wk4[i] = wkp[i]; wv4[i] = wvp[i]; }
    }
    const float qe = qemb[oc];

    // ---- Stage: x halo -> xs, coalesced float4 (1152 float4 over 256 thr).
#pragma unroll
    for (int r = 0; r < 5; ++r) {
        const int f = t + r * 256;
        if (f < NPIX_HALO * CG / 4) {
            const int hp = f >> 3, c4 = f & 7;        // 8 float4 per pixel
            const int hi = hp / HT, hj = hp % HT;
            const int gh = h0 + hi, gw = w0 + hj;
            float4 val = make_float4(0.f, 0.f, 0.f, 0.f);
            if (gh >= 0 && gh < TH && gw >= 0 && gw < TW)
                val = *(const float4*)(x + (((size_t)b * TH + gh) * TW + gw) * TC
                                         + g * CG + c4 * 4);
            *(float4*)&xs[hp][c4 * 4] = val;
        }
    }

    __syncthreads();   // stage -> merged pass

    // ---- Merged QKV pass, 2 pixels per iteration (9 iters).
#pragma unroll 1
    for (int it = 0; it < 9; ++it) {
        const int hpA = it * 16 + p0;        // both rows owned by group p0
        const int hpB = hpA + 8;
        const float4* xpA = (const float4*)&xs[hpA][0];
        const float4* xpB = (const float4*)&xs[hpB][0];
        float aqA = qe, akA = 0.f, avA = 0.f;
        float aqB = qe, akB = 0.f, avB = 0.f;
#pragma unroll
        for (int i = 0; i < 8; ++i) {
            const float4 xa = xpA[i];
            const float4 xb = xpB[i];
            const float4 q4 = wq4[i], k4 = wk4[i], v4 = wv4[i];
            aqA = fmaf(q4.x, xa.x, aqA); akA = fmaf(k4.x, xa.x, akA); avA = fmaf(v4.x, xa.x, avA);
            aqB = fmaf(q4.x, xb.x, aqB); akB = fmaf(k4.x, xb.x, akB); avB = fmaf(v4.x, xb.x, avB);
            aqA = fmaf(q4.y, xa.y, aqA); akA = fmaf(k4.y, xa.y, akA); avA = fmaf(v4.y, xa.y, avA);
            aqB = fmaf(q4.y, xb.y, aqB); akB = fmaf(k4.y, xb.y, akB); avB = fmaf(v4.y, xb.y, avB);
            aqA = fmaf(q4.z, xa.z, aqA); akA = fmaf(k4.z, xa.z, akA); avA = fmaf(v4.z, xa.z, avA);
            aqB = fmaf(q4.z, xb.z, aqB); akB = fmaf(k4.z, xb.z, akB); avB = fmaf(v4.z, xb.z, avB);
            aqA = fmaf(q4.w, xa.w, aqA); akA = fmaf(k4.w, xa.w, akA); avA = fmaf(v4.w, xa.w, avA);
            aqB = fmaf(q4.w, xb.w, aqB); akB = fmaf(k4.w, xb.w, akB); avB = fmaf(v4.w, xb.w, avB);
        }
        // pack k,v -> bf16 (round-half-up) in one u32; overwrite rows in place
        const unsigned kbA = __float_as_uint(akA) + 0x8000u;
        const unsigned vbA = __float_as_uint(avA) + 0x8000u;
        ((unsigned*)&xs[hpA][0])[c] = (kbA >> 16) | (vbA & 0xffff0000u);
        const unsigned kbB = __float_as_uint(akB) + 0x8000u;
        const unsigned vbB = __float_as_uint(avB) + 0x8000u;
        ((unsigned*)&xs[hpB][0])[c] = (kbB >> 16) | (vbB & 0xffff0000u);

        const int hiA = hpA / HT, hjA = hpA % HT;
        if (hiA >= PAD && hiA < PAD + TILE && hjA >= PAD && hjA < PAD + TILE)
            qs[(hiA - PAD) * TILE + (hjA - PAD)][c] = aqA * LOG2E;
        const int hiB = hpB / HT, hjB = hpB % HT;
        if (hiB >= PAD && hiB < PAD + TILE && hjB >= PAD && hjB < PAD + TILE)
            qs[(hiB - PAD) * TILE + (hjB - PAD)][c] = aqB * LOG2E;
    }

    // rel row for this channel (global, L2-hot) while waiting on barrier
    const float* rp = rel + (size_t)oc * 25;
    float relr[25];
#pragma unroll
    for (int i = 0; i < 25; ++i) relr[i] = rp[i];

    __syncthreads();   // merged pass -> C

    // q (already *log2e) for this thread's 8 column pixels
    float qreg[8];
#pragma unroll
    for (int ii = 0; ii < 8; ++ii) qreg[ii] = qs[ii * TILE + p0][c];

    // ---- Phase C: row-streaming attention (xs holds packed bf16 k,v).
    float s_[8], a_[8];
#pragma unroll
    for (int ii = 0; ii < 8; ++ii) { s_[ii] = 0.f; a_[ii] = 0.f; }

    const unsigned* kvp = (const unsigned*)&xs[0][0];
#pragma unroll
    for (int h = 0; h < HT; ++h) {
        float kr[5], vr[5];
#pragma unroll
        for (int j = 0; j < 5; ++j) {
            const unsigned u = kvp[(h * HT + p0 + j) * CG + c];
            kr[j] = __uint_as_float(u << 16);          // bf16 k -> f32
            vr[j] = __uint_as_float(u & 0xffff0000u);  // bf16 v -> f32
        }
#pragma unroll
        for (int ii = 0; ii < 8; ++ii) {
            const int di = h - ii;               // compile-time after unroll
            if (di >= 0 && di < 5) {
                const float qv = qreg[ii];
#pragma unroll
                for (int j = 0; j < 5; ++j) {
                    const float e = __builtin_amdgcn_exp2f(qv * (kr[j] + relr[di * 5 + j]));
                    s_[ii] += e;
                    a_[ii] = fmaf(e, vr[j], a_[ii]);
                }
            }
        }
    }

#pragma unroll
    for (int ii = 0; ii < 8; ++ii) {
        const int gh = ti * TILE + ii, gw = tj * TILE + p0;
        out[(((size_t)b * TH + gh) * TW + gw) * TC + g * CG + c] =
            a_[ii] * __builtin_amdgcn_rcpf(s_[ii]);
    }
}

extern "C" void kernel_launch(void* const* d_in, const int* in_sizes, int n_in,
                              void* d_out, int out_size, void* d_ws, size_t ws_size,
                              hipStream_t stream) {
    const float* x    = (const float*)d_in[0];
    const float* wq   = (const float*)d_in[1];
    const float* wk   = (const float*)d_in[2];
    const float* wv   = (const float*)d_in[3];
    const float* rel  = (const float*)d_in[4];
    const float* qemb = (const float*)d_in[5];
    float* out = (float*)d_out;

    const int nblocks = TB * NT * NT * G;   // 4*7*7*8 = 1568
    hipLaunchKernelGGL(fused_attn_conv_kernel, dim3(nblocks), dim3(256), 0, stream,
                       x, wq, wk, wv, rel, qemb, out);
}